// Round 7
// baseline (383.807 us; speedup 1.0000x reference)
//
#include <hip/hip_runtime.h>
#include <math.h>

#define N_NODES 20000
#define N_EDGES 400000
#define BATCH   4096

// ---- xl = x@Wl, xr = x@Wr  (x: [N][K], W: [K][128], out: [N][128])
// 256 threads: t<128 -> Wl/xl column t, t>=128 -> Wr/xr column t-128.
// G=16 nodes/block -> 1250 blocks x 4 waves ~ 19.5 waves/CU.
// W registers double-buffered to hide L2 latency under the FMA block.
template<int K, int G>
__global__ __launch_bounds__(256)
void transform_lr_kernel(const float* __restrict__ x,
                         const float* __restrict__ Wl,
                         const float* __restrict__ Wr,
                         float* __restrict__ xl,
                         float* __restrict__ xr)
{
    const int col = threadIdx.x & 127;
    const int sel = threadIdx.x >> 7;           // wave-uniform
    const float* __restrict__ W   = sel ? Wr : Wl;
    float* __restrict__       out = sel ? xr : xl;
    const int n0 = blockIdx.x * G;
    const float* __restrict__ xb = x + (size_t)n0 * K;

    float acc[G];
#pragma unroll
    for (int g = 0; g < G; ++g) acc[g] = 0.f;

    float wc[4];
#pragma unroll
    for (int u = 0; u < 4; ++u) wc[u] = W[u * 128 + col];

    for (int k0 = 0; k0 < K; k0 += 4) {
        float wn[4];
        if (k0 + 4 < K) {
#pragma unroll
            for (int u = 0; u < 4; ++u) wn[u] = W[(k0 + 4 + u) * 128 + col];
        }
#pragma unroll
        for (int g = 0; g < G; ++g) {
            const float4 xv = *(const float4*)(xb + g * K + k0);  // uniform -> s_load
            acc[g] = fmaf(xv.x, wc[0], acc[g]);
            acc[g] = fmaf(xv.y, wc[1], acc[g]);
            acc[g] = fmaf(xv.z, wc[2], acc[g]);
            acc[g] = fmaf(xv.w, wc[3], acc[g]);
        }
#pragma unroll
        for (int u = 0; u < 4; ++u) wc[u] = wn[u];
    }
#pragma unroll
    for (int g = 0; g < G; ++g)
        out[(size_t)(n0 + g) * 128 + col] = acc[g];
}

// ---- single-transform variant (layer 3 xl): 256 threads = 2 node-groups of G.
template<int K, int G>
__global__ __launch_bounds__(256)
void transform_l_kernel(const float* __restrict__ x,
                        const float* __restrict__ W,
                        float* __restrict__ out)
{
    const int col  = threadIdx.x & 127;
    const int half = threadIdx.x >> 7;
    const int n0 = blockIdx.x * (2 * G) + half * G;
    const float* __restrict__ xb = x + (size_t)n0 * K;

    float acc[G];
#pragma unroll
    for (int g = 0; g < G; ++g) acc[g] = 0.f;

    float wc[4];
#pragma unroll
    for (int u = 0; u < 4; ++u) wc[u] = W[u * 128 + col];

    for (int k0 = 0; k0 < K; k0 += 4) {
        float wn[4];
        if (k0 + 4 < K) {
#pragma unroll
            for (int u = 0; u < 4; ++u) wn[u] = W[(k0 + 4 + u) * 128 + col];
        }
#pragma unroll
        for (int g = 0; g < G; ++g) {
            const float4 xv = *(const float4*)(xb + g * K + k0);
            acc[g] = fmaf(xv.x, wc[0], acc[g]);
            acc[g] = fmaf(xv.y, wc[1], acc[g]);
            acc[g] = fmaf(xv.z, wc[2], acc[g]);
            acc[g] = fmaf(xv.w, wc[3], acc[g]);
        }
#pragma unroll
        for (int u = 0; u < 4; ++u) wc[u] = wn[u];
    }
#pragma unroll
    for (int g = 0; g < G; ++g)
        out[(size_t)(n0 + g) * 128 + col] = acc[g];
}

// ---- layer-3 xr only for the 4096 pert rows: out[i] = x[pert[i]] @ W
template<int K>
__global__ __launch_bounds__(128)
void transform_r_pert_kernel(const float* __restrict__ x,
                             const int* __restrict__ pert,
                             const float* __restrict__ W,
                             float* __restrict__ out)
{
    const int t  = threadIdx.x;
    const int i0 = blockIdx.x * 16;

    int pn[16];
#pragma unroll
    for (int g = 0; g < 16; ++g) pn[g] = pert[i0 + g];   // uniform s_loads

    float acc[16];
#pragma unroll
    for (int g = 0; g < 16; ++g) acc[g] = 0.f;

    float wc[4];
#pragma unroll
    for (int u = 0; u < 4; ++u) wc[u] = W[u * 128 + t];

    for (int k0 = 0; k0 < K; k0 += 4) {
        float wn[4];
        if (k0 + 4 < K) {
#pragma unroll
            for (int u = 0; u < 4; ++u) wn[u] = W[(k0 + 4 + u) * 128 + t];
        }
#pragma unroll
        for (int g = 0; g < 16; ++g) {
            const float4 xv = *(const float4*)(x + (size_t)pn[g] * K + k0);
            acc[g] = fmaf(xv.x, wc[0], acc[g]);
            acc[g] = fmaf(xv.y, wc[1], acc[g]);
            acc[g] = fmaf(xv.z, wc[2], acc[g]);
            acc[g] = fmaf(xv.w, wc[3], acc[g]);
        }
#pragma unroll
        for (int u = 0; u < 4; ++u) wc[u] = wn[u];
    }
#pragma unroll
    for (int g = 0; g < 16; ++g)
        out[(size_t)(i0 + g) * 128 + t] = acc[g];
}

// ---- zero an int buffer
__global__ __launch_bounds__(256)
void zero_kernel(int* __restrict__ p, int n)
{
    const int i = blockIdx.x * blockDim.x + threadIdx.x;
    if (i < n) p[i] = 0;
}

// ---- CSR build: count degrees
__global__ __launch_bounds__(256)
void count_deg_kernel(const int* __restrict__ dst, int* __restrict__ deg, int E)
{
    const int e = blockIdx.x * blockDim.x + threadIdx.x;
    if (e < E) atomicAdd(&deg[dst[e]], 1);
}

// ---- exclusive scan over 20000 degrees; one block, LDS-staged coalesced I/O.
#define CHUNK 20
#define SCAN_PAD (1024 * CHUNK)
__global__ __launch_bounds__(1024)
void scan_kernel(const int* __restrict__ deg, int* __restrict__ off,
                 int* __restrict__ cursor)
{
    __shared__ int xs[SCAN_PAD];    // 80 KB (+ pad)
    __shared__ int sums[1024];
    const int t = threadIdx.x;
    for (int i = t; i < SCAN_PAD; i += 1024)
        xs[i] = (i < N_NODES) ? deg[i] : 0;
    __syncthreads();

    const int base = t * CHUNK;
    int local[CHUNK];
    int s = 0;
#pragma unroll
    for (int i = 0; i < CHUNK; ++i) {
        local[i] = s;
        s += xs[base + i];
    }
    sums[t] = s;
    __syncthreads();
    for (int d = 1; d < 1024; d <<= 1) {
        int v = (t >= d) ? sums[t - d] : 0;
        __syncthreads();
        sums[t] += v;
        __syncthreads();
    }
    const int prev = (t == 0) ? 0 : sums[t - 1];
#pragma unroll
    for (int i = 0; i < CHUNK; ++i)
        xs[base + i] = prev + local[i];
    __syncthreads();
    for (int i = t; i < N_NODES; i += 1024) {
        const int o = xs[i];
        off[i] = o;
        cursor[i] = o;
    }
    if (t == 1023) off[N_NODES] = sums[1023];
}

// ---- scatter edges into dst-sorted order
__global__ __launch_bounds__(256)
void scatter_kernel(const int* __restrict__ src, const int* __restrict__ dst,
                    const float* __restrict__ ew, int* __restrict__ cursor,
                    int* __restrict__ ssrc, float* __restrict__ sew, int E)
{
    const int e = blockIdx.x * blockDim.x + threadIdx.x;
    if (e >= E) return;
    const int p = atomicAdd(&cursor[dst[e]], 1);
    ssrc[p] = src[e];
    sew[p]  = ew[e];
}

// ---- fused GATv2 layer: one wave per dst node, 4 edge slots in parallel.
// lane = q*16 + h*8 + j : q = edge slot (4), h = head (2), j = dim chunk (8 dims).
// LAST: edges/off indexed by nodemap[widx]; xr indexed by widx (pert-row buffer).
template<int LAST>
__global__ __launch_bounds__(256)
void gat_node_kernel(const float* __restrict__ xl, const float* __restrict__ xr,
                     const int* __restrict__ off, const int* __restrict__ ssrc,
                     const float* __restrict__ sew, const float* __restrict__ a,
                     const float* __restrict__ b, float* __restrict__ xout,
                     const int* __restrict__ nodemap, int nnodes)
{
    const int widx = (int)((blockIdx.x * blockDim.x + threadIdx.x) >> 6);
    if (widx >= nnodes) return;
    const int node = LAST ? nodemap[widx] : widx;
    const int xrrow = LAST ? widx : widx;   // xr row: batch idx for LAST, node otherwise
    const int lane = threadIdx.x & 63;
    const int q  = lane >> 4;
    const int h  = (lane >> 3) & 1;
    const int j  = lane & 7;
    const int cb = h * 64 + j * 8;   // column base in [0,128)

    const float4 xrA = *(const float4*)(xr + (size_t)xrrow * 128 + cb);
    const float4 xrB = *(const float4*)(xr + (size_t)xrrow * 128 + cb + 4);
    const float4 aA  = *(const float4*)(a + cb);
    const float4 aB  = *(const float4*)(a + cb + 4);

    const int e0 = off[node], e1 = off[node + 1];

    float m = -1e30f, s = 0.f;
    float acc[8];
#pragma unroll
    for (int k = 0; k < 8; ++k) acc[k] = 0.f;

    for (int ebase = e0; ebase < e1; ebase += 4) {
        const int  ei    = ebase + q;
        const bool valid = ei < e1;
        const int  eic   = valid ? ei : (e1 - 1);
        const int  sn    = ssrc[eic];
        const float w    = valid ? sew[eic] : 0.f;
        const float4 xA = *(const float4*)(xl + (size_t)sn * 128 + cb);
        const float4 xB = *(const float4*)(xl + (size_t)sn * 128 + cb + 4);

        float v0 = xA.x + xrA.x, v1 = xA.y + xrA.y;
        float v2 = xA.z + xrA.z, v3 = xA.w + xrA.w;
        float v4 = xB.x + xrB.x, v5 = xB.y + xrB.y;
        float v6 = xB.z + xrB.z, v7 = xB.w + xrB.w;
        v0 = fmaxf(v0, 0.2f * v0); v1 = fmaxf(v1, 0.2f * v1);
        v2 = fmaxf(v2, 0.2f * v2); v3 = fmaxf(v3, 0.2f * v3);
        v4 = fmaxf(v4, 0.2f * v4); v5 = fmaxf(v5, 0.2f * v5);
        v6 = fmaxf(v6, 0.2f * v6); v7 = fmaxf(v7, 0.2f * v7);
        float t0 = fmaf(v0, aA.x, v1 * aA.y);
        float t1 = fmaf(v2, aA.z, v3 * aA.w);
        float t2 = fmaf(v4, aB.x, v5 * aB.y);
        float t3 = fmaf(v6, aB.z, v7 * aB.w);
        float p = (t0 + t1) + (t2 + t3);
        p += __shfl_xor(p, 1, 64);
        p += __shfl_xor(p, 2, 64);
        p += __shfl_xor(p, 4, 64);
        p = valid ? p : -1e30f;

        // online softmax (one native exp per round per lane)
        const float d   = p - m;
        const float t   = __expf(-fabsf(d));
        const bool  pos = d > 0.f;
        const float r   = pos ? t : 1.f;
        const float ex  = pos ? 1.f : t;
        m = pos ? p : m;
        const float c = ex * w;
        s = s * r + ex;
        acc[0] = acc[0] * r + c * xA.x;
        acc[1] = acc[1] * r + c * xA.y;
        acc[2] = acc[2] * r + c * xA.z;
        acc[3] = acc[3] * r + c * xA.w;
        acc[4] = acc[4] * r + c * xB.x;
        acc[5] = acc[5] * r + c * xB.y;
        acc[6] = acc[6] * r + c * xB.z;
        acc[7] = acc[7] * r + c * xB.w;
    }

    // ---- merge the 4 slot states (across q: lane strides 16, 32)
    float mg = fmaxf(m, __shfl_xor(m, 16, 64));
    mg = fmaxf(mg, __shfl_xor(mg, 32, 64));
    const float rq = __expf(m - mg);        // 0 for dead slots
    float sq = s * rq;
    sq += __shfl_xor(sq, 16, 64);
    sq += __shfl_xor(sq, 32, 64);
#pragma unroll
    for (int k = 0; k < 8; ++k) {
        float v = acc[k] * rq;
        v += __shfl_xor(v, 16, 64);
        v += __shfl_xor(v, 32, 64);
        acc[k] = v;
    }
    const float inv = 1.f / (sq + 1e-16f);

    if (!LAST) {
        if (q == 0) {
            float o[8];
#pragma unroll
            for (int k = 0; k < 8; ++k) {
                float u = acc[k] * inv + b[cb + k];
                o[k] = u > 0.f ? u : expm1f(u);
            }
            *(float4*)(xout + (size_t)node * 128 + cb)     = make_float4(o[0], o[1], o[2], o[3]);
            *(float4*)(xout + (size_t)node * 128 + cb + 4) = make_float4(o[4], o[5], o[6], o[7]);
        }
    } else {
        float o[8];
#pragma unroll
        for (int k = 0; k < 8; ++k) {
            const float v = acc[k] * inv;
            o[k] = 0.5f * (v + __shfl_xor(v, 8, 64)) + b[j * 8 + k];
        }
        if (q == 0 && h == 0) {
            *(float4*)(xout + (size_t)widx * 64 + j * 8)     = make_float4(o[0], o[1], o[2], o[3]);
            *(float4*)(xout + (size_t)widx * 64 + j * 8 + 4) = make_float4(o[4], o[5], o[6], o[7]);
        }
    }
}

extern "C" void kernel_launch(void* const* d_in, const int* in_sizes, int n_in,
                              void* d_out, int out_size, void* d_ws, size_t ws_size,
                              hipStream_t stream)
{
    const int*   pert = (const int*)d_in[0];
    const int*   eidx = (const int*)d_in[1];
    const float* ew   = (const float*)d_in[2];
    const float* emb  = (const float*)d_in[3];
    const float* Wl[4] = {(const float*)d_in[4],  (const float*)d_in[8],
                          (const float*)d_in[12], (const float*)d_in[16]};
    const float* Wr[4] = {(const float*)d_in[5],  (const float*)d_in[9],
                          (const float*)d_in[13], (const float*)d_in[17]};
    const float* av[4] = {(const float*)d_in[6],  (const float*)d_in[10],
                          (const float*)d_in[14], (const float*)d_in[18]};
    const float* bv[4] = {(const float*)d_in[7],  (const float*)d_in[11],
                          (const float*)d_in[15], (const float*)d_in[19]};

    const int N = N_NODES, E = N_EDGES;
    const int* srcp = eidx;
    const int* dstp = eidx + E;

    // workspace layout
    float* ws   = (float*)d_ws;
    float* xbuf = ws;                              // N*128 f
    float* xl   = xbuf + (size_t)N * 128;          // N*128 f
    float* xr   = xl   + (size_t)N * 128;          // N*128 f (layer3: 4096 pert rows)
    int*   deg  = (int*)(xr + (size_t)N * 128);    // N     i
    int*   off  = deg + N;                         // N+1   i
    int*   cur  = off + N + 1;                     // N     i
    int*   ssrc = cur + N;                         // E     i
    float* sew  = (float*)(ssrc + E);              // E     f

    // ---- build dst-sorted CSR once (graph static across layers)
    zero_kernel<<<(N + 255) / 256, 256, 0, stream>>>(deg, N);
    count_deg_kernel<<<(E + 255) / 256, 256, 0, stream>>>(dstp, deg, E);
    scan_kernel<<<1, 1024, 0, stream>>>(deg, off, cur);
    scatter_kernel<<<(E + 255) / 256, 256, 0, stream>>>(srcp, dstp, ew, cur,
                                                        ssrc, sew, E);

    const float* x = emb;
    for (int layer = 0; layer < 3; ++layer) {
        if (layer == 0)
            transform_lr_kernel<64, 16><<<N / 16, 256, 0, stream>>>(
                x, Wl[layer], Wr[layer], xl, xr);
        else
            transform_lr_kernel<128, 16><<<N / 16, 256, 0, stream>>>(
                x, Wl[layer], Wr[layer], xl, xr);

        gat_node_kernel<0><<<(N * 64 + 255) / 256, 256, 0, stream>>>(
            xl, xr, off, ssrc, sew, av[layer], bv[layer], xbuf, nullptr, N);
        x = xbuf;
    }

    // ---- layer 3: xl for all nodes, xr only for pert rows
    transform_l_kernel<128, 8><<<N / 16, 256, 0, stream>>>(x, Wl[3], xl);
    transform_r_pert_kernel<128><<<BATCH / 16, 128, 0, stream>>>(x, pert, Wr[3], xr);
    gat_node_kernel<1><<<(BATCH * 64 + 255) / 256, 256, 0, stream>>>(
        xl, xr, off, ssrc, sew, av[3], bv[3], (float*)d_out, pert, BATCH);
}

// Round 8
// 343.490 us; speedup vs baseline: 1.1174x; 1.1174x over previous
//
#include <hip/hip_runtime.h>
#include <math.h>

#define N_NODES 20000
#define N_EDGES 400000
#define BATCH   4096

// ---- xl = x@Wl (+ xr = x@Wr if DUAL). x: [N][K], W: [K][128], out: [N][128].
// 128 threads (one output column each), G nodes per block.
// Ping-pong double-buffer of BOTH x and W: each FMA block hides the next
// chunk's load latency (round-7 lesson: un-prefetched x loads serialize).
template<int K, int G, bool DUAL>
__global__ __launch_bounds__(128)
void transform_kernel(const float* __restrict__ x,
                      const float* __restrict__ Wl,
                      const float* __restrict__ Wr,
                      float* __restrict__ xl,
                      float* __restrict__ xr)
{
    const int t  = threadIdx.x;
    const int n0 = blockIdx.x * G;
    const float* __restrict__ xb = x + (size_t)n0 * K;

    float accl[G], accr[G];
#pragma unroll
    for (int g = 0; g < G; ++g) { accl[g] = 0.f; accr[g] = 0.f; }

    float4 xA[G], xB[G];
    float wlA[4], wrA[4], wlB[4], wrB[4];

    auto loadc = [&](float4* xs, float* wl, float* wr, int k) {
#pragma unroll
        for (int g = 0; g < G; ++g)
            xs[g] = *(const float4*)(xb + g * K + k);
#pragma unroll
        for (int u = 0; u < 4; ++u) {
            wl[u] = Wl[(k + u) * 128 + t];
            if constexpr (DUAL) wr[u] = Wr[(k + u) * 128 + t];
        }
    };
    auto fmac = [&](const float4* xs, const float* wl, const float* wr) {
#pragma unroll
        for (int g = 0; g < G; ++g) {
            accl[g] = fmaf(xs[g].x, wl[0], accl[g]);
            accl[g] = fmaf(xs[g].y, wl[1], accl[g]);
            accl[g] = fmaf(xs[g].z, wl[2], accl[g]);
            accl[g] = fmaf(xs[g].w, wl[3], accl[g]);
            if constexpr (DUAL) {
                accr[g] = fmaf(xs[g].x, wr[0], accr[g]);
                accr[g] = fmaf(xs[g].y, wr[1], accr[g]);
                accr[g] = fmaf(xs[g].z, wr[2], accr[g]);
                accr[g] = fmaf(xs[g].w, wr[3], accr[g]);
            }
        }
    };

    loadc(xA, wlA, wrA, 0);
    for (int k0 = 0; k0 < K; k0 += 8) {
        if (k0 + 4 < K) loadc(xB, wlB, wrB, k0 + 4);
        fmac(xA, wlA, wrA);
        if (k0 + 8 < K) loadc(xA, wlA, wrA, k0 + 8);
        fmac(xB, wlB, wrB);
    }

#pragma unroll
    for (int g = 0; g < G; ++g) {
        xl[(size_t)(n0 + g) * 128 + t] = accl[g];
        if constexpr (DUAL) xr[(size_t)(n0 + g) * 128 + t] = accr[g];
    }
}

// ---- layer-3 xr only for the 4096 pert rows (same pipelined structure)
template<int K, int G>
__global__ __launch_bounds__(128)
void transform_r_pert_kernel(const float* __restrict__ x,
                             const int* __restrict__ pert,
                             const float* __restrict__ W,
                             float* __restrict__ out)
{
    const int t  = threadIdx.x;
    const int i0 = blockIdx.x * G;

    const float* __restrict__ xrow[G];
#pragma unroll
    for (int g = 0; g < G; ++g)
        xrow[g] = x + (size_t)pert[i0 + g] * K;

    float acc[G];
#pragma unroll
    for (int g = 0; g < G; ++g) acc[g] = 0.f;

    float4 xA[G], xB[G];
    float wA[4], wB[4];

    auto loadc = [&](float4* xs, float* w, int k) {
#pragma unroll
        for (int g = 0; g < G; ++g)
            xs[g] = *(const float4*)(xrow[g] + k);
#pragma unroll
        for (int u = 0; u < 4; ++u) w[u] = W[(k + u) * 128 + t];
    };
    auto fmac = [&](const float4* xs, const float* w) {
#pragma unroll
        for (int g = 0; g < G; ++g) {
            acc[g] = fmaf(xs[g].x, w[0], acc[g]);
            acc[g] = fmaf(xs[g].y, w[1], acc[g]);
            acc[g] = fmaf(xs[g].z, w[2], acc[g]);
            acc[g] = fmaf(xs[g].w, w[3], acc[g]);
        }
    };

    loadc(xA, wA, 0);
    for (int k0 = 0; k0 < K; k0 += 8) {
        if (k0 + 4 < K) loadc(xB, wB, k0 + 4);
        fmac(xA, wA);
        if (k0 + 8 < K) loadc(xA, wA, k0 + 8);
        fmac(xB, wB);
    }

#pragma unroll
    for (int g = 0; g < G; ++g)
        out[(size_t)(i0 + g) * 128 + t] = acc[g];
}

// ---- zero an int buffer
__global__ __launch_bounds__(256)
void zero_kernel(int* __restrict__ p, int n)
{
    const int i = blockIdx.x * blockDim.x + threadIdx.x;
    if (i < n) p[i] = 0;
}

// ---- CSR build: count degrees
__global__ __launch_bounds__(256)
void count_deg_kernel(const int* __restrict__ dst, int* __restrict__ deg, int E)
{
    const int e = blockIdx.x * blockDim.x + threadIdx.x;
    if (e < E) atomicAdd(&deg[dst[e]], 1);
}

// ---- exclusive scan over 20000 degrees; one block, LDS-staged coalesced I/O.
#define CHUNK 20
#define SCAN_PAD (1024 * CHUNK)
__global__ __launch_bounds__(1024)
void scan_kernel(const int* __restrict__ deg, int* __restrict__ off,
                 int* __restrict__ cursor)
{
    __shared__ int xs[SCAN_PAD];    // 80 KB (+ pad)
    __shared__ int sums[1024];
    const int t = threadIdx.x;
    for (int i = t; i < SCAN_PAD; i += 1024)
        xs[i] = (i < N_NODES) ? deg[i] : 0;
    __syncthreads();

    const int base = t * CHUNK;
    int local[CHUNK];
    int s = 0;
#pragma unroll
    for (int i = 0; i < CHUNK; ++i) {
        local[i] = s;
        s += xs[base + i];
    }
    sums[t] = s;
    __syncthreads();
    for (int d = 1; d < 1024; d <<= 1) {
        int v = (t >= d) ? sums[t - d] : 0;
        __syncthreads();
        sums[t] += v;
        __syncthreads();
    }
    const int prev = (t == 0) ? 0 : sums[t - 1];
#pragma unroll
    for (int i = 0; i < CHUNK; ++i)
        xs[base + i] = prev + local[i];
    __syncthreads();
    for (int i = t; i < N_NODES; i += 1024) {
        const int o = xs[i];
        off[i] = o;
        cursor[i] = o;
    }
    if (t == 1023) off[N_NODES] = sums[1023];
}

// ---- scatter edges into dst-sorted order
__global__ __launch_bounds__(256)
void scatter_kernel(const int* __restrict__ src, const int* __restrict__ dst,
                    const float* __restrict__ ew, int* __restrict__ cursor,
                    int* __restrict__ ssrc, float* __restrict__ sew, int E)
{
    const int e = blockIdx.x * blockDim.x + threadIdx.x;
    if (e >= E) return;
    const int p = atomicAdd(&cursor[dst[e]], 1);
    ssrc[p] = src[e];
    sew[p]  = ew[e];
}

// ---- fused GATv2 layer: one wave per dst node, 4 edge slots in parallel.
// lane = q*16 + h*8 + j : q = edge slot (4), h = head (2), j = dim chunk (8 dims).
// LAST: edges/off indexed by nodemap[widx]; xr indexed by widx (pert-row buffer).
template<int LAST>
__global__ __launch_bounds__(256)
void gat_node_kernel(const float* __restrict__ xl, const float* __restrict__ xr,
                     const int* __restrict__ off, const int* __restrict__ ssrc,
                     const float* __restrict__ sew, const float* __restrict__ a,
                     const float* __restrict__ b, float* __restrict__ xout,
                     const int* __restrict__ nodemap, int nnodes)
{
    const int widx = (int)((blockIdx.x * blockDim.x + threadIdx.x) >> 6);
    if (widx >= nnodes) return;
    const int node = LAST ? nodemap[widx] : widx;
    const int xrrow = widx;          // == node for !LAST; batch row for LAST
    const int lane = threadIdx.x & 63;
    const int q  = lane >> 4;
    const int h  = (lane >> 3) & 1;
    const int j  = lane & 7;
    const int cb = h * 64 + j * 8;   // column base in [0,128)

    const float4 xrA = *(const float4*)(xr + (size_t)xrrow * 128 + cb);
    const float4 xrB = *(const float4*)(xr + (size_t)xrrow * 128 + cb + 4);
    const float4 aA  = *(const float4*)(a + cb);
    const float4 aB  = *(const float4*)(a + cb + 4);

    const int e0 = off[node], e1 = off[node + 1];

    float m = -1e30f, s = 0.f;
    float acc[8];
#pragma unroll
    for (int k = 0; k < 8; ++k) acc[k] = 0.f;

    for (int ebase = e0; ebase < e1; ebase += 4) {
        const int  ei    = ebase + q;
        const bool valid = ei < e1;
        const int  eic   = valid ? ei : (e1 - 1);
        const int  sn    = ssrc[eic];
        const float w    = valid ? sew[eic] : 0.f;
        const float4 xA = *(const float4*)(xl + (size_t)sn * 128 + cb);
        const float4 xB = *(const float4*)(xl + (size_t)sn * 128 + cb + 4);

        float v0 = xA.x + xrA.x, v1 = xA.y + xrA.y;
        float v2 = xA.z + xrA.z, v3 = xA.w + xrA.w;
        float v4 = xB.x + xrB.x, v5 = xB.y + xrB.y;
        float v6 = xB.z + xrB.z, v7 = xB.w + xrB.w;
        v0 = fmaxf(v0, 0.2f * v0); v1 = fmaxf(v1, 0.2f * v1);
        v2 = fmaxf(v2, 0.2f * v2); v3 = fmaxf(v3, 0.2f * v3);
        v4 = fmaxf(v4, 0.2f * v4); v5 = fmaxf(v5, 0.2f * v5);
        v6 = fmaxf(v6, 0.2f * v6); v7 = fmaxf(v7, 0.2f * v7);
        float t0 = fmaf(v0, aA.x, v1 * aA.y);
        float t1 = fmaf(v2, aA.z, v3 * aA.w);
        float t2 = fmaf(v4, aB.x, v5 * aB.y);
        float t3 = fmaf(v6, aB.z, v7 * aB.w);
        float p = (t0 + t1) + (t2 + t3);
        p += __shfl_xor(p, 1, 64);
        p += __shfl_xor(p, 2, 64);
        p += __shfl_xor(p, 4, 64);
        p = valid ? p : -1e30f;

        // online softmax (one native exp per round per lane)
        const float d   = p - m;
        const float t   = __expf(-fabsf(d));
        const bool  pos = d > 0.f;
        const float r   = pos ? t : 1.f;
        const float ex  = pos ? 1.f : t;
        m = pos ? p : m;
        const float c = ex * w;
        s = s * r + ex;
        acc[0] = acc[0] * r + c * xA.x;
        acc[1] = acc[1] * r + c * xA.y;
        acc[2] = acc[2] * r + c * xA.z;
        acc[3] = acc[3] * r + c * xA.w;
        acc[4] = acc[4] * r + c * xB.x;
        acc[5] = acc[5] * r + c * xB.y;
        acc[6] = acc[6] * r + c * xB.z;
        acc[7] = acc[7] * r + c * xB.w;
    }

    // ---- merge the 4 slot states (across q: lane strides 16, 32)
    float mg = fmaxf(m, __shfl_xor(m, 16, 64));
    mg = fmaxf(mg, __shfl_xor(mg, 32, 64));
    const float rq = __expf(m - mg);        // 0 for dead slots
    float sq = s * rq;
    sq += __shfl_xor(sq, 16, 64);
    sq += __shfl_xor(sq, 32, 64);
#pragma unroll
    for (int k = 0; k < 8; ++k) {
        float v = acc[k] * rq;
        v += __shfl_xor(v, 16, 64);
        v += __shfl_xor(v, 32, 64);
        acc[k] = v;
    }
    const float inv = 1.f / (sq + 1e-16f);

    if (!LAST) {
        if (q == 0) {
            float o[8];
#pragma unroll
            for (int k = 0; k < 8; ++k) {
                float u = acc[k] * inv + b[cb + k];
                o[k] = u > 0.f ? u : expm1f(u);
            }
            *(float4*)(xout + (size_t)node * 128 + cb)     = make_float4(o[0], o[1], o[2], o[3]);
            *(float4*)(xout + (size_t)node * 128 + cb + 4) = make_float4(o[4], o[5], o[6], o[7]);
        }
    } else {
        float o[8];
#pragma unroll
        for (int k = 0; k < 8; ++k) {
            const float v = acc[k] * inv;
            o[k] = 0.5f * (v + __shfl_xor(v, 8, 64)) + b[j * 8 + k];
        }
        if (q == 0 && h == 0) {
            *(float4*)(xout + (size_t)widx * 64 + j * 8)     = make_float4(o[0], o[1], o[2], o[3]);
            *(float4*)(xout + (size_t)widx * 64 + j * 8 + 4) = make_float4(o[4], o[5], o[6], o[7]);
        }
    }
}

extern "C" void kernel_launch(void* const* d_in, const int* in_sizes, int n_in,
                              void* d_out, int out_size, void* d_ws, size_t ws_size,
                              hipStream_t stream)
{
    const int*   pert = (const int*)d_in[0];
    const int*   eidx = (const int*)d_in[1];
    const float* ew   = (const float*)d_in[2];
    const float* emb  = (const float*)d_in[3];
    const float* Wl[4] = {(const float*)d_in[4],  (const float*)d_in[8],
                          (const float*)d_in[12], (const float*)d_in[16]};
    const float* Wr[4] = {(const float*)d_in[5],  (const float*)d_in[9],
                          (const float*)d_in[13], (const float*)d_in[17]};
    const float* av[4] = {(const float*)d_in[6],  (const float*)d_in[10],
                          (const float*)d_in[14], (const float*)d_in[18]};
    const float* bv[4] = {(const float*)d_in[7],  (const float*)d_in[11],
                          (const float*)d_in[15], (const float*)d_in[19]};

    const int N = N_NODES, E = N_EDGES;
    const int* srcp = eidx;
    const int* dstp = eidx + E;

    // workspace layout
    float* ws   = (float*)d_ws;
    float* xbuf = ws;                              // N*128 f
    float* xl   = xbuf + (size_t)N * 128;          // N*128 f
    float* xr   = xl   + (size_t)N * 128;          // N*128 f (layer3: 4096 pert rows)
    int*   deg  = (int*)(xr + (size_t)N * 128);    // N     i
    int*   off  = deg + N;                         // N+1   i
    int*   cur  = off + N + 1;                     // N     i
    int*   ssrc = cur + N;                         // E     i
    float* sew  = (float*)(ssrc + E);              // E     f

    // ---- build dst-sorted CSR once (graph static across layers)
    zero_kernel<<<(N + 255) / 256, 256, 0, stream>>>(deg, N);
    count_deg_kernel<<<(E + 255) / 256, 256, 0, stream>>>(dstp, deg, E);
    scan_kernel<<<1, 1024, 0, stream>>>(deg, off, cur);
    scatter_kernel<<<(E + 255) / 256, 256, 0, stream>>>(srcp, dstp, ew, cur,
                                                        ssrc, sew, E);

    const float* x = emb;
    for (int layer = 0; layer < 3; ++layer) {
        if (layer == 0)
            transform_kernel<64, 8, true><<<N / 8, 128, 0, stream>>>(
                x, Wl[layer], Wr[layer], xl, xr);
        else
            transform_kernel<128, 8, true><<<N / 8, 128, 0, stream>>>(
                x, Wl[layer], Wr[layer], xl, xr);

        gat_node_kernel<0><<<(N * 64 + 255) / 256, 256, 0, stream>>>(
            xl, xr, off, ssrc, sew, av[layer], bv[layer], xbuf, nullptr, N);
        x = xbuf;
    }

    // ---- layer 3: xl for all nodes, xr only for pert rows
    transform_kernel<128, 8, false><<<N / 8, 128, 0, stream>>>(
        x, Wl[3], nullptr, xl, nullptr);
    transform_r_pert_kernel<128, 8><<<BATCH / 8, 128, 0, stream>>>(
        x, pert, Wr[3], xr);
    gat_node_kernel<1><<<(BATCH * 64 + 255) / 256, 256, 0, stream>>>(
        xl, xr, off, ssrc, sew, av[3], bv[3], (float*)d_out, pert, BATCH);
}

// Round 9
// 327.066 us; speedup vs baseline: 1.1735x; 1.0502x over previous
//
#include <hip/hip_runtime.h>
#include <math.h>

#define N_NODES 20000
#define N_EDGES 400000
#define BATCH   4096

// ---- xl = x@Wl (+ xr = x@Wr if DUAL). x: [N][K], W: [K][128], out: [N][128].
// 256 threads, 16 nodes/block. x-tile staged into LDS ONCE (coalesced, fully
// parallel) -- kills the per-iteration L2-miss latency that pinned previous
// versions at 44 us. k-loop: x via broadcast ds_read_b128 + W via L2 loads,
// both register ping-pong double-buffered under the FMA blocks.
// Thread t: col = t&127, node-half = (t>>7)*8.
template<int K, bool DUAL>
__global__ __launch_bounds__(256)
void transform_kernel(const float* __restrict__ x,
                      const float* __restrict__ Wl,
                      const float* __restrict__ Wr,
                      float* __restrict__ xl,
                      float* __restrict__ xr)
{
    __shared__ float xs[16 * K];
    const int t   = threadIdx.x;
    const int col = t & 127;
    const int hs  = (t >> 7) * 8;        // node sub-block: 0 or 8
    const int n0  = blockIdx.x * 16;

    // cooperative stage: 16*K floats as float4 (K=64: 1/thread, K=128: 2/thread)
    {
        const float4* __restrict__ src = (const float4*)(x + (size_t)n0 * K);
        float4* dst = (float4*)xs;
#pragma unroll
        for (int i = 0; i < (16 * K / 4 + 255) / 256; ++i) {
            const int idx = t + i * 256;
            if (idx < 16 * K / 4) dst[idx] = src[idx];
        }
    }
    __syncthreads();

    float accl[8], accr[8];
#pragma unroll
    for (int g = 0; g < 8; ++g) { accl[g] = 0.f; accr[g] = 0.f; }

    float4 xA[8], xB[8];
    float wlA[4], wrA[4], wlB[4], wrB[4];

    auto loadW = [&](float* wl, float* wr, int k) {
#pragma unroll
        for (int u = 0; u < 4; ++u) {
            wl[u] = Wl[(k + u) * 128 + col];
            if constexpr (DUAL) wr[u] = Wr[(k + u) * 128 + col];
        }
    };
    auto loadX = [&](float4* xv, int k) {
#pragma unroll
        for (int g = 0; g < 8; ++g)
            xv[g] = *(const float4*)(xs + (hs + g) * K + k);
    };
    auto fmac = [&](const float4* xv, const float* wl, const float* wr) {
#pragma unroll
        for (int g = 0; g < 8; ++g) {
            accl[g] = fmaf(xv[g].x, wl[0], accl[g]);
            accl[g] = fmaf(xv[g].y, wl[1], accl[g]);
            accl[g] = fmaf(xv[g].z, wl[2], accl[g]);
            accl[g] = fmaf(xv[g].w, wl[3], accl[g]);
            if constexpr (DUAL) {
                accr[g] = fmaf(xv[g].x, wr[0], accr[g]);
                accr[g] = fmaf(xv[g].y, wr[1], accr[g]);
                accr[g] = fmaf(xv[g].z, wr[2], accr[g]);
                accr[g] = fmaf(xv[g].w, wr[3], accr[g]);
            }
        }
    };

    loadW(wlA, wrA, 0);
    loadX(xA, 0);
    for (int k0 = 0; k0 < K; k0 += 8) {
        if (k0 + 4 < K) { loadW(wlB, wrB, k0 + 4); loadX(xB, k0 + 4); }
        fmac(xA, wlA, wrA);
        if (k0 + 8 < K) { loadW(wlA, wrA, k0 + 8); loadX(xA, k0 + 8); }
        fmac(xB, wlB, wrB);
    }

#pragma unroll
    for (int g = 0; g < 8; ++g) {
        xl[(size_t)(n0 + hs + g) * 128 + col] = accl[g];
        if constexpr (DUAL) xr[(size_t)(n0 + hs + g) * 128 + col] = accr[g];
    }
}

// ---- layer-3 xr only for the 4096 pert rows (register-pipelined, gathered x)
template<int K, int G>
__global__ __launch_bounds__(128)
void transform_r_pert_kernel(const float* __restrict__ x,
                             const int* __restrict__ pert,
                             const float* __restrict__ W,
                             float* __restrict__ out)
{
    const int t  = threadIdx.x;
    const int i0 = blockIdx.x * G;

    const float* __restrict__ xrow[G];
#pragma unroll
    for (int g = 0; g < G; ++g)
        xrow[g] = x + (size_t)pert[i0 + g] * K;

    float acc[G];
#pragma unroll
    for (int g = 0; g < G; ++g) acc[g] = 0.f;

    float4 xA[G], xB[G];
    float wA[4], wB[4];

    auto loadc = [&](float4* xs, float* w, int k) {
#pragma unroll
        for (int g = 0; g < G; ++g)
            xs[g] = *(const float4*)(xrow[g] + k);
#pragma unroll
        for (int u = 0; u < 4; ++u) w[u] = W[(k + u) * 128 + t];
    };
    auto fmac = [&](const float4* xs, const float* w) {
#pragma unroll
        for (int g = 0; g < G; ++g) {
            acc[g] = fmaf(xs[g].x, w[0], acc[g]);
            acc[g] = fmaf(xs[g].y, w[1], acc[g]);
            acc[g] = fmaf(xs[g].z, w[2], acc[g]);
            acc[g] = fmaf(xs[g].w, w[3], acc[g]);
        }
    };

    loadc(xA, wA, 0);
    for (int k0 = 0; k0 < K; k0 += 8) {
        if (k0 + 4 < K) loadc(xB, wB, k0 + 4);
        fmac(xA, wA);
        if (k0 + 8 < K) loadc(xA, wA, k0 + 8);
        fmac(xB, wB);
    }

#pragma unroll
    for (int g = 0; g < G; ++g)
        out[(size_t)(i0 + g) * 128 + t] = acc[g];
}

// ---- zero an int buffer
__global__ __launch_bounds__(256)
void zero_kernel(int* __restrict__ p, int n)
{
    const int i = blockIdx.x * blockDim.x + threadIdx.x;
    if (i < n) p[i] = 0;
}

// ---- CSR build: count degrees
__global__ __launch_bounds__(256)
void count_deg_kernel(const int* __restrict__ dst, int* __restrict__ deg, int E)
{
    const int e = blockIdx.x * blockDim.x + threadIdx.x;
    if (e < E) atomicAdd(&deg[dst[e]], 1);
}

// ---- exclusive scan over 20000 degrees; one block, LDS-staged coalesced I/O.
#define CHUNK 20
#define SCAN_PAD (1024 * CHUNK)
__global__ __launch_bounds__(1024)
void scan_kernel(const int* __restrict__ deg, int* __restrict__ off,
                 int* __restrict__ cursor)
{
    __shared__ int xs[SCAN_PAD];    // 80 KB (+ pad)
    __shared__ int sums[1024];
    const int t = threadIdx.x;
    for (int i = t; i < SCAN_PAD; i += 1024)
        xs[i] = (i < N_NODES) ? deg[i] : 0;
    __syncthreads();

    const int base = t * CHUNK;
    int local[CHUNK];
    int s = 0;
#pragma unroll
    for (int i = 0; i < CHUNK; ++i) {
        local[i] = s;
        s += xs[base + i];
    }
    sums[t] = s;
    __syncthreads();
    for (int d = 1; d < 1024; d <<= 1) {
        int v = (t >= d) ? sums[t - d] : 0;
        __syncthreads();
        sums[t] += v;
        __syncthreads();
    }
    const int prev = (t == 0) ? 0 : sums[t - 1];
#pragma unroll
    for (int i = 0; i < CHUNK; ++i)
        xs[base + i] = prev + local[i];
    __syncthreads();
    for (int i = t; i < N_NODES; i += 1024) {
        const int o = xs[i];
        off[i] = o;
        cursor[i] = o;
    }
    if (t == 1023) off[N_NODES] = sums[1023];
}

// ---- scatter edges into dst-sorted order
__global__ __launch_bounds__(256)
void scatter_kernel(const int* __restrict__ src, const int* __restrict__ dst,
                    const float* __restrict__ ew, int* __restrict__ cursor,
                    int* __restrict__ ssrc, float* __restrict__ sew, int E)
{
    const int e = blockIdx.x * blockDim.x + threadIdx.x;
    if (e >= E) return;
    const int p = atomicAdd(&cursor[dst[e]], 1);
    ssrc[p] = src[e];
    sew[p]  = ew[e];
}

// ---- fused GATv2 layer: one wave per dst node, 4 edge slots in parallel.
// lane = q*16 + h*8 + j : q = edge slot (4), h = head (2), j = dim chunk (8 dims).
// LAST: edges/off indexed by nodemap[widx]; xr indexed by widx (pert-row buffer).
template<int LAST>
__global__ __launch_bounds__(256)
void gat_node_kernel(const float* __restrict__ xl, const float* __restrict__ xr,
                     const int* __restrict__ off, const int* __restrict__ ssrc,
                     const float* __restrict__ sew, const float* __restrict__ a,
                     const float* __restrict__ b, float* __restrict__ xout,
                     const int* __restrict__ nodemap, int nnodes)
{
    const int widx = (int)((blockIdx.x * blockDim.x + threadIdx.x) >> 6);
    if (widx >= nnodes) return;
    const int node = LAST ? nodemap[widx] : widx;
    const int xrrow = widx;          // == node for !LAST; batch row for LAST
    const int lane = threadIdx.x & 63;
    const int q  = lane >> 4;
    const int h  = (lane >> 3) & 1;
    const int j  = lane & 7;
    const int cb = h * 64 + j * 8;   // column base in [0,128)

    const float4 xrA = *(const float4*)(xr + (size_t)xrrow * 128 + cb);
    const float4 xrB = *(const float4*)(xr + (size_t)xrrow * 128 + cb + 4);
    const float4 aA  = *(const float4*)(a + cb);
    const float4 aB  = *(const float4*)(a + cb + 4);

    const int e0 = off[node], e1 = off[node + 1];

    float m = -1e30f, s = 0.f;
    float acc[8];
#pragma unroll
    for (int k = 0; k < 8; ++k) acc[k] = 0.f;

    for (int ebase = e0; ebase < e1; ebase += 4) {
        const int  ei    = ebase + q;
        const bool valid = ei < e1;
        const int  eic   = valid ? ei : (e1 - 1);
        const int  sn    = ssrc[eic];
        const float w    = valid ? sew[eic] : 0.f;
        const float4 xA = *(const float4*)(xl + (size_t)sn * 128 + cb);
        const float4 xB = *(const float4*)(xl + (size_t)sn * 128 + cb + 4);

        float v0 = xA.x + xrA.x, v1 = xA.y + xrA.y;
        float v2 = xA.z + xrA.z, v3 = xA.w + xrA.w;
        float v4 = xB.x + xrB.x, v5 = xB.y + xrB.y;
        float v6 = xB.z + xrB.z, v7 = xB.w + xrB.w;
        v0 = fmaxf(v0, 0.2f * v0); v1 = fmaxf(v1, 0.2f * v1);
        v2 = fmaxf(v2, 0.2f * v2); v3 = fmaxf(v3, 0.2f * v3);
        v4 = fmaxf(v4, 0.2f * v4); v5 = fmaxf(v5, 0.2f * v5);
        v6 = fmaxf(v6, 0.2f * v6); v7 = fmaxf(v7, 0.2f * v7);
        float t0 = fmaf(v0, aA.x, v1 * aA.y);
        float t1 = fmaf(v2, aA.z, v3 * aA.w);
        float t2 = fmaf(v4, aB.x, v5 * aB.y);
        float t3 = fmaf(v6, aB.z, v7 * aB.w);
        float p = (t0 + t1) + (t2 + t3);
        p += __shfl_xor(p, 1, 64);
        p += __shfl_xor(p, 2, 64);
        p += __shfl_xor(p, 4, 64);
        p = valid ? p : -1e30f;

        // online softmax (one native exp per round per lane)
        const float d   = p - m;
        const float t   = __expf(-fabsf(d));
        const bool  pos = d > 0.f;
        const float r   = pos ? t : 1.f;
        const float ex  = pos ? 1.f : t;
        m = pos ? p : m;
        const float c = ex * w;
        s = s * r + ex;
        acc[0] = acc[0] * r + c * xA.x;
        acc[1] = acc[1] * r + c * xA.y;
        acc[2] = acc[2] * r + c * xA.z;
        acc[3] = acc[3] * r + c * xA.w;
        acc[4] = acc[4] * r + c * xB.x;
        acc[5] = acc[5] * r + c * xB.y;
        acc[6] = acc[6] * r + c * xB.z;
        acc[7] = acc[7] * r + c * xB.w;
    }

    // ---- merge the 4 slot states (across q: lane strides 16, 32)
    float mg = fmaxf(m, __shfl_xor(m, 16, 64));
    mg = fmaxf(mg, __shfl_xor(mg, 32, 64));
    const float rq = __expf(m - mg);        // 0 for dead slots
    float sq = s * rq;
    sq += __shfl_xor(sq, 16, 64);
    sq += __shfl_xor(sq, 32, 64);
#pragma unroll
    for (int k = 0; k < 8; ++k) {
        float v = acc[k] * rq;
        v += __shfl_xor(v, 16, 64);
        v += __shfl_xor(v, 32, 64);
        acc[k] = v;
    }
    const float inv = 1.f / (sq + 1e-16f);

    if (!LAST) {
        if (q == 0) {
            float o[8];
#pragma unroll
            for (int k = 0; k < 8; ++k) {
                float u = acc[k] * inv + b[cb + k];
                o[k] = u > 0.f ? u : expm1f(u);
            }
            *(float4*)(xout + (size_t)node * 128 + cb)     = make_float4(o[0], o[1], o[2], o[3]);
            *(float4*)(xout + (size_t)node * 128 + cb + 4) = make_float4(o[4], o[5], o[6], o[7]);
        }
    } else {
        float o[8];
#pragma unroll
        for (int k = 0; k < 8; ++k) {
            const float v = acc[k] * inv;
            o[k] = 0.5f * (v + __shfl_xor(v, 8, 64)) + b[j * 8 + k];
        }
        if (q == 0 && h == 0) {
            *(float4*)(xout + (size_t)widx * 64 + j * 8)     = make_float4(o[0], o[1], o[2], o[3]);
            *(float4*)(xout + (size_t)widx * 64 + j * 8 + 4) = make_float4(o[4], o[5], o[6], o[7]);
        }
    }
}

extern "C" void kernel_launch(void* const* d_in, const int* in_sizes, int n_in,
                              void* d_out, int out_size, void* d_ws, size_t ws_size,
                              hipStream_t stream)
{
    const int*   pert = (const int*)d_in[0];
    const int*   eidx = (const int*)d_in[1];
    const float* ew   = (const float*)d_in[2];
    const float* emb  = (const float*)d_in[3];
    const float* Wl[4] = {(const float*)d_in[4],  (const float*)d_in[8],
                          (const float*)d_in[12], (const float*)d_in[16]};
    const float* Wr[4] = {(const float*)d_in[5],  (const float*)d_in[9],
                          (const float*)d_in[13], (const float*)d_in[17]};
    const float* av[4] = {(const float*)d_in[6],  (const float*)d_in[10],
                          (const float*)d_in[14], (const float*)d_in[18]};
    const float* bv[4] = {(const float*)d_in[7],  (const float*)d_in[11],
                          (const float*)d_in[15], (const float*)d_in[19]};

    const int N = N_NODES, E = N_EDGES;
    const int* srcp = eidx;
    const int* dstp = eidx + E;

    // workspace layout
    float* ws   = (float*)d_ws;
    float* xbuf = ws;                              // N*128 f
    float* xl   = xbuf + (size_t)N * 128;          // N*128 f
    float* xr   = xl   + (size_t)N * 128;          // N*128 f (layer3: 4096 pert rows)
    int*   deg  = (int*)(xr + (size_t)N * 128);    // N     i
    int*   off  = deg + N;                         // N+1   i
    int*   cur  = off + N + 1;                     // N     i
    int*   ssrc = cur + N;                         // E     i
    float* sew  = (float*)(ssrc + E);              // E     f

    // ---- build dst-sorted CSR once (graph static across layers)
    zero_kernel<<<(N + 255) / 256, 256, 0, stream>>>(deg, N);
    count_deg_kernel<<<(E + 255) / 256, 256, 0, stream>>>(dstp, deg, E);
    scan_kernel<<<1, 1024, 0, stream>>>(deg, off, cur);
    scatter_kernel<<<(E + 255) / 256, 256, 0, stream>>>(srcp, dstp, ew, cur,
                                                        ssrc, sew, E);

    const float* x = emb;
    for (int layer = 0; layer < 3; ++layer) {
        if (layer == 0)
            transform_kernel<64, true><<<N / 16, 256, 0, stream>>>(
                x, Wl[layer], Wr[layer], xl, xr);
        else
            transform_kernel<128, true><<<N / 16, 256, 0, stream>>>(
                x, Wl[layer], Wr[layer], xl, xr);

        gat_node_kernel<0><<<(N * 64 + 255) / 256, 256, 0, stream>>>(
            xl, xr, off, ssrc, sew, av[layer], bv[layer], xbuf, nullptr, N);
        x = xbuf;
    }

    // ---- layer 3: xl for all nodes, xr only for pert rows
    transform_kernel<128, false><<<N / 16, 256, 0, stream>>>(
        x, Wl[3], nullptr, xl, nullptr);
    transform_r_pert_kernel<128, 8><<<BATCH / 8, 128, 0, stream>>>(
        x, pert, Wr[3], xr);
    gat_node_kernel<1><<<(BATCH * 64 + 255) / 256, 256, 0, stream>>>(
        xl, xr, off, ssrc, sew, av[3], bv[3], (float*)d_out, pert, BATCH);
}